// Round 8
// baseline (304.723 us; speedup 1.0000x reference)
//
#include <hip/hip_runtime.h>
#include <hip/hip_bf16.h>
#include <cstdint>
#include <cstddef>

// Problem: B=4, T=4096, D=1024, H=16, HD=64.
// qkv = x @ Wqkv; per-token 16x16 head-attention; out = ao @ Wout.
//
// ROUND 8 = MEASUREMENT ROUND (GEMM schedule frozen at R7's fine-phase
// structure, the 898-TF plateau reached by 8 structural variants):
// 1) GEMM1 split into its 3 natural N=1024 slices (q/k/v weight bands are
//    contiguous in the permuted layout) so every kernel is <= ~40 us and the
//    rocprof top-5 window MUST reveal the ~120 us of currently-invisible
//    non-GEMM time (attn? gaps?) with full counters.
// 2) cvt + both weight transposes fused into one grid-partitioned prep
//    kernel (2 fewer launches; tests the launch-gap hypothesis).
// No arithmetic changes anywhere: same tiles, same accumulation order.

typedef __bf16 bf16x8 __attribute__((ext_vector_type(8)));
typedef __bf16 bf16x4 __attribute__((ext_vector_type(4)));
typedef float  f32x4  __attribute__((ext_vector_type(4)));

#define AS1 __attribute__((address_space(1)))
#define AS3 __attribute__((address_space(3)))

__device__ __forceinline__ void async_copy16(const void* g, void* l) {
    __builtin_amdgcn_global_load_lds((const AS1 void*)g, (AS3 void*)l, 16, 0, 0);
}

// position p in the permuted qkv token-row holds original column pi(p).
// q/k (g<2): col=g*1024+h*64+d -> p = g*1024 + (d&32)*16 + ((d>>3)&3)*128 + h*8 + (d&7)
// v (g==2): col=2048+j*64+d -> p = 2048 + d*16 + j (V transposed)
// NOTE: group g maps into permuted rows [g*1024, (g+1)*1024) -> weight bands
// are contiguous -> GEMM1 splits into 3 independent N=1024 GEMMs.
__device__ __forceinline__ int invp_qkv(int col) {
    int g = col >> 10;
    if (g == 2) { int q = col & 1023; return 2048 + ((q & 63) << 4) + (q >> 6); }
    int h = (col >> 6) & 15, d = col & 63;
    return (g << 10) + ((d & 32) << 4) + (((d >> 3) & 3) << 7) + (h << 3) + (d & 7);
}

// ao position map: original k = i*64+d -> p = (i>>2)*256 + (d&15)*16 + (d>>4)*4 + (i&3)
__device__ __forceinline__ int invp_ao(int k) {
    return (((k >> 8) & 3) << 8) + ((k & 15) << 4) + (((k >> 4) & 3) << 2) + ((k >> 6) & 3);
}

// ---------------- fused prep: cvt x -> bf16, transpose+permute both weights ----
// grid partition: blocks [0,2048) cvt (8 float4/thread), [2048,5120) Wqkv
// transpose (32x32 tile each), [5120,6144) Wout transpose.
__global__ __launch_bounds__(256) void prep_kernel(const float4* __restrict__ x4,
                                                   bf16x4* __restrict__ xb4,
                                                   const float* __restrict__ Wqkv,
                                                   __bf16* __restrict__ wqkvT,
                                                   const float* __restrict__ Wout,
                                                   __bf16* __restrict__ woutT) {
    __shared__ float tile[32][33];
    const int b = blockIdx.x;
    if (b < 2048) {
        // cvt: 2048 blocks x 256 threads x 8 float4 = 4194304 float4s
        const int base = b * 2048 + threadIdx.x;
        #pragma unroll
        for (int i = 0; i < 8; ++i) {
            const int idx = base + i * 256;
            float4 v = x4[idx];
            bf16x4 o = { (__bf16)v.x, (__bf16)v.y, (__bf16)v.z, (__bf16)v.w };
            xb4[idx] = o;
        }
        return;
    }
    const int tx = threadIdx.x & 31, ty = threadIdx.x >> 5; // 32 x 8
    if (b < 2048 + 3072) {
        // Wqkv transpose+permute: 96 x 32 tiles
        const int bb = b - 2048;
        const int c0 = (bb % 96) * 32, r0 = (bb / 96) * 32;
        const int C = 3072;
        #pragma unroll
        for (int i = 0; i < 32; i += 8)
            tile[ty + i][tx] = Wqkv[(size_t)(r0 + ty + i) * C + c0 + tx];
        __syncthreads();
        #pragma unroll
        for (int i = 0; i < 32; i += 8) {
            int prow = invp_qkv(c0 + ty + i);
            wqkvT[(size_t)prow * 1024 + r0 + tx] = (__bf16)tile[tx][ty + i];
        }
    } else {
        // Wout transpose+permute: 32 x 32 tiles
        const int bb = b - (2048 + 3072);
        const int c0 = (bb % 32) * 32, r0 = (bb / 32) * 32;
        const int C = 1024;
        #pragma unroll
        for (int i = 0; i < 32; i += 8)
            tile[ty + i][tx] = Wout[(size_t)(r0 + ty + i) * C + c0 + tx];
        __syncthreads();
        int pk = invp_ao(r0 + tx);
        #pragma unroll
        for (int i = 0; i < 32; i += 8)
            woutT[(size_t)(c0 + ty + i) * 1024 + pk] = (__bf16)tile[tx][ty + i];
    }
}

// ---------------- bf16 GEMM, C = A @ Bt^T, 256x256 tile, BK=64, fine phases ----
// (R7 structure, frozen.) A: M x K bf16 row-major, Bt: N x K bf16 row-major
// with N = 1024 per dispatch (nbx=4, nby=64, grid 256, XCD-band swizzle).
// C written at stride ldc (3072 for qkv slices, 1024 for out).
// 512 threads = 8 waves (2Mx4N), wave-tile 128x64, acc[8][4]. LDS: single
// buffer A 256x64 + B 256x64 = 64 KiB; row = 128 B = 8 slots, phys = slot ^
// (row&7) (0 conflicts measured); staged via pre-swizzled global source.
// 4 sub-phases per K-tile with in-place staging; vmcnt gates 2/2/4,
// never drained to 0 mid-loop (full WAR/RAW ledger in round-7 notes).
template<int OUT_BF16>
__global__ __launch_bounds__(512, 2) void gemm_bt(const __bf16* __restrict__ A,
                                                  const __bf16* __restrict__ Bt,
                                                  void* __restrict__ Cv,
                                                  int ldc, int K) {
    __shared__ __attribute__((aligned(16))) __bf16 As[256 * 64]; // 32 KB
    __shared__ __attribute__((aligned(16))) __bf16 Bs[256 * 64]; // 32 KB

    const int lin = blockIdx.x;
    const int xcd = lin & 7;
    const int rr  = lin >> 3;
    const int by  = xcd * 8 + (rr & 7);
    const int bx  = rr >> 3;

    const int tid  = threadIdx.x;
    const int wave = tid >> 6;
    const int lane = tid & 63;
    const int quad = lane >> 4;
    const int q16  = lane & 15;
    const int wr   = wave >> 2, wc = wave & 3;  // 2 x 4 wave grid
    const int row0 = by * 256;
    const int col0 = bx * 256;

    const __bf16* Ag = A  + (size_t)row0 * K;
    const __bf16* Bg = Bt + (size_t)col0 * K;

    const int rowIdx = tid >> 3;
    const int slotq  = tid & 7;
    const int skel   = ((slotq ^ (rowIdx & 7)) << 3);
    const int brg    = rowIdx + (rowIdx & 32);
    const __bf16* aSrc = Ag + (size_t)rowIdx * K + skel;
    const __bf16* bSrc = Bg + (size_t)brg * K + skel;
    char* aDst = (char*)As + rowIdx * 128 + slotq * 16;
    char* bDst = (char*)Bs + brg * 128 + slotq * 16;

    const int px0   = ((quad ^ (q16 & 7)) << 4);
    const int px1   = px0 ^ 64;
    const int aBase = (wr * 128 + q16) * 128;
    const int bBase = (wc * 64 + q16) * 128;
    const char* AsB = (const char*)As;
    const char* BsB = (const char*)Bs;

    f32x4 acc[8][4] = {};
    bf16x8 af[4][2], bf[4][2];

    const int NT = K >> 6;

#define STAGE_A(t, u) do { \
        const size_t ko_ = (size_t)(t) * 64; \
        const int b0_ = (u) ? 64 : 0, b1_ = (u) ? 192 : 128; \
        async_copy16(aSrc + (size_t)b0_ * K + ko_, aDst + b0_ * 128); \
        async_copy16(aSrc + (size_t)b1_ * K + ko_, aDst + b1_ * 128); \
    } while (0)
#define STAGE_B(t, u) do { \
        const size_t ko_ = (size_t)(t) * 64; \
        const int s0_ = (u) ? 32 : 0, s1_ = (u) ? 160 : 128; \
        async_copy16(bSrc + (size_t)s0_ * K + ko_, bDst + s0_ * 128); \
        async_copy16(bSrc + (size_t)s1_ * K + ko_, bDst + s1_ * 128); \
    } while (0)
#define SB0() __builtin_amdgcn_sched_barrier(0)
#define MFMA_Q(a, b) do { \
        _Pragma("unroll") \
        for (int kk = 0; kk < 2; ++kk) \
            _Pragma("unroll") \
            for (int mi = 0; mi < 4; ++mi) \
                _Pragma("unroll") \
                for (int ni = (b)*2; ni < (b)*2 + 2; ++ni) \
                    acc[(a)*4 + mi][ni] = __builtin_amdgcn_mfma_f32_16x16x32_bf16( \
                        af[mi][kk], bf[ni][kk], acc[(a)*4 + mi][ni], 0, 0, 0); \
    } while (0)

    STAGE_A(0, 0); STAGE_B(0, 0); STAGE_B(0, 1); STAGE_A(0, 1);
    asm volatile("s_waitcnt vmcnt(0)" ::: "memory");
    __builtin_amdgcn_s_barrier();
    SB0();

    #pragma unroll 1
    for (int t = 0; t < NT; ++t) {
        const bool pf = (t + 1 < NT);

        // ---- phase 1: read A-u1 (mi0-3) + B-u1 (ni0-1) | MFMA Q00 ----
        #pragma unroll
        for (int mi = 0; mi < 4; ++mi) {
            af[mi][0] = *(const bf16x8*)(AsB + aBase + mi * 2048 + px0);
            af[mi][1] = *(const bf16x8*)(AsB + aBase + mi * 2048 + px1);
        }
        #pragma unroll
        for (int ni = 0; ni < 2; ++ni) {
            bf[ni][0] = *(const bf16x8*)(BsB + bBase + ni * 2048 + px0);
            bf[ni][1] = *(const bf16x8*)(BsB + bBase + ni * 2048 + px1);
        }
        SB0();
        __builtin_amdgcn_s_barrier();
        asm volatile("s_waitcnt lgkmcnt(0)" ::: "memory");
        SB0();
        __builtin_amdgcn_s_setprio(1);
        MFMA_Q(0, 0);
        __builtin_amdgcn_s_setprio(0);
        SB0();
        asm volatile("s_waitcnt vmcnt(2)" ::: "memory"); // Bu2(t) landed for ph2
        __builtin_amdgcn_s_barrier();
        SB0();

        // ---- phase 2: read B-u2 (ni2-3) | stage A-u1(t+1) | MFMA Q01 ----
        #pragma unroll
        for (int ni = 2; ni < 4; ++ni) {
            bf[ni][0] = *(const bf16x8*)(BsB + bBase + ni * 2048 + px0);
            bf[ni][1] = *(const bf16x8*)(BsB + bBase + ni * 2048 + px1);
        }
        if (pf) STAGE_A(t + 1, 0);
        SB0();
        __builtin_amdgcn_s_barrier();
        asm volatile("s_waitcnt lgkmcnt(0)" ::: "memory");
        SB0();
        __builtin_amdgcn_s_setprio(1);
        MFMA_Q(0, 1);
        __builtin_amdgcn_s_setprio(0);
        SB0();
        asm volatile("s_waitcnt vmcnt(2)" ::: "memory"); // Au2(t) landed for ph3
        __builtin_amdgcn_s_barrier();
        SB0();

        // ---- phase 3: read A-u2 (mi4-7) | stage B-u1,B-u2(t+1) | MFMA Q10 ----
        #pragma unroll
        for (int mi = 0; mi < 4; ++mi) {
            af[mi][0] = *(const bf16x8*)(AsB + aBase + 8192 + mi * 2048 + px0);
            af[mi][1] = *(const bf16x8*)(AsB + aBase + 8192 + mi * 2048 + px1);
        }
        if (pf) { STAGE_B(t + 1, 0); STAGE_B(t + 1, 1); }
        SB0();
        __builtin_amdgcn_s_barrier();
        asm volatile("s_waitcnt lgkmcnt(0)" ::: "memory");
        SB0();
        __builtin_amdgcn_s_setprio(1);
        MFMA_Q(1, 0);
        __builtin_amdgcn_s_setprio(0);
        SB0();
        __builtin_amdgcn_s_barrier();
        SB0();

        // ---- phase 4: stage A-u2(t+1) | MFMA Q11 | gate for ph1(t+1) ----
        if (pf) STAGE_A(t + 1, 1);
        SB0();
        __builtin_amdgcn_s_barrier();
        SB0();
        __builtin_amdgcn_s_setprio(1);
        MFMA_Q(1, 1);
        __builtin_amdgcn_s_setprio(0);
        SB0();
        asm volatile("s_waitcnt vmcnt(4)" ::: "memory"); // Au1',Bu1' landed
        __builtin_amdgcn_s_barrier();
        SB0();
    }
#undef MFMA_Q
#undef SB0
#undef STAGE_B
#undef STAGE_A

    // epilogue: D row = quad*4 + r, col = q16 (per 16x16 tile), stride ldc
    #pragma unroll
    for (int mi = 0; mi < 8; ++mi) {
        #pragma unroll
        for (int ni = 0; ni < 4; ++ni) {
            const int col = col0 + wc * 64 + ni * 16 + q16;
            #pragma unroll
            for (int r = 0; r < 4; ++r) {
                const int row = row0 + wr * 128 + mi * 16 + quad * 4 + r;
                if (OUT_BF16)
                    ((__bf16*)Cv)[(size_t)row * ldc + col] = (__bf16)acc[mi][ni][r];
                else
                    ((float*)Cv)[(size_t)row * ldc + col] = acc[mi][ni][r];
            }
        }
    }
}

// ---------------- per-token head attention, MFMA, one wave per token ----------------
__global__ __launch_bounds__(256) void attn_mfma_kernel(const __bf16* __restrict__ qkv,
                                                        __bf16* __restrict__ ao) {
    const int tok  = blockIdx.x * 4 + (threadIdx.x >> 6);
    const int lane = threadIdx.x & 63;
    const int quad = lane >> 4;
    const int q16  = lane & 15;

    const __bf16* base = qkv + (size_t)tok * 3072;

    const bf16x8 qf0 = *(const bf16x8*)(base + lane * 8);
    const bf16x8 qf1 = *(const bf16x8*)(base + 512 + lane * 8);
    const bf16x8 kf0 = *(const bf16x8*)(base + 1024 + lane * 8);
    const bf16x8 kf1 = *(const bf16x8*)(base + 1536 + lane * 8);

    f32x4 st = {0.f, 0.f, 0.f, 0.f};
    st = __builtin_amdgcn_mfma_f32_16x16x32_bf16(kf0, qf0, st, 0, 0, 0);
    st = __builtin_amdgcn_mfma_f32_16x16x32_bf16(kf1, qf1, st, 0, 0, 0);

    float s0 = st[0] * 0.125f, s1 = st[1] * 0.125f, s2 = st[2] * 0.125f, s3 = st[3] * 0.125f;
    float m = fmaxf(fmaxf(s0, s1), fmaxf(s2, s3));
    m = fmaxf(m, __shfl_xor(m, 16));
    m = fmaxf(m, __shfl_xor(m, 32));
    float e0 = __expf(s0 - m), e1 = __expf(s1 - m), e2 = __expf(s2 - m), e3 = __expf(s3 - m);
    float sum = e0 + e1 + e2 + e3;
    sum += __shfl_xor(sum, 16);
    sum += __shfl_xor(sum, 32);
    const float inv = 1.f / sum;

    union { __bf16 h[2]; int i; } u01, u23;
    u01.h[0] = (__bf16)(e0 * inv); u01.h[1] = (__bf16)(e1 * inv);
    u23.h[0] = (__bf16)(e2 * inv); u23.h[1] = (__bf16)(e3 * inv);

    const int src0 = quad * 32 + q16;
    const int src1 = src0 + 16;
    union { int i[4]; bf16x8 v; } af;
    af.i[0] = __shfl(u01.i, src0);
    af.i[1] = __shfl(u23.i, src0);
    af.i[2] = __shfl(u01.i, src1);
    af.i[3] = __shfl(u23.i, src1);
    if (quad >= 2) { af.i[0] = 0; af.i[1] = 0; af.i[2] = 0; af.i[3] = 0; }

    const __bf16* vb = base + 2048;
    f32x4 accs[4];
    #pragma unroll
    for (int c = 0; c < 4; ++c) {
        bf16x8 bfv = {};
        if (quad < 2)
            bfv = *(const bf16x8*)(vb + (c * 16 + q16) * 16 + quad * 8);
        f32x4 z = {0.f, 0.f, 0.f, 0.f};
        accs[c] = __builtin_amdgcn_mfma_f32_16x16x32_bf16(af.v, bfv, z, 0, 0, 0);
    }

    union { __bf16 h[16]; bf16x8 v[2]; } o;
    #pragma unroll
    for (int c = 0; c < 4; ++c)
        #pragma unroll
        for (int r = 0; r < 4; ++r)
            o.h[c * 4 + r] = (__bf16)accs[c][r];
    __bf16* outp = ao + (size_t)tok * 1024 + lane * 16;
    *(bf16x8*)outp = o.v[0];
    *(bf16x8*)(outp + 8) = o.v[1];
}

// ---------------- launch ----------------
extern "C" void kernel_launch(void* const* d_in, const int* in_sizes, int n_in,
                              void* d_out, int out_size, void* d_ws, size_t ws_size,
                              hipStream_t stream) {
    const float* x    = (const float*)d_in[0]; // 16384 x 1024
    const float* Wqkv = (const float*)d_in[1]; // 1024 x 3072
    const float* Wout = (const float*)d_in[2]; // 1024 x 1024
    float* out = (float*)d_out;                // 16384 x 1024

    char* ws = (char*)d_ws;
    __bf16* xb    = (__bf16*)(ws);                                   // 32 MiB
    __bf16* wqkvT = (__bf16*)(ws + 33554432);                        // 6 MiB  (3072 x 1024, row-permuted)
    __bf16* woutT = (__bf16*)(ws + 33554432 + 6291456);              // 2 MiB  (1024 x 1024, k-permuted)
    __bf16* qkv   = (__bf16*)(ws + 33554432 + 6291456 + 2097152);    // 96 MiB (16384 x 3072, permuted)
    __bf16* ao    = (__bf16*)(ws + 33554432 + 6291456 + 2097152 + 100663296); // 32 MiB (permuted)

    // fused prep: cvt x (2048 blocks) + Wqkv transpose (3072) + Wout (1024)
    prep_kernel<<<6144, 256, 0, stream>>>((const float4*)x, (bf16x4*)xb,
                                          Wqkv, wqkvT, Wout, woutT);
    // GEMM1 split into q/k/v slices (N=1024 each, grid 256, C stride 3072):
    // weight band g occupies permuted rows [g*1024,(g+1)*1024) of wqkvT and
    // permuted cols [g*1024,(g+1)*1024) of qkv.
    gemm_bt<1><<<256, 512, 0, stream>>>(xb, wqkvT,                  (void*)qkv,          3072, 1024);
    gemm_bt<1><<<256, 512, 0, stream>>>(xb, wqkvT + (size_t)1024 * 1024, (void*)(qkv + 1024), 3072, 1024);
    gemm_bt<1><<<256, 512, 0, stream>>>(xb, wqkvT + (size_t)2048 * 1024, (void*)(qkv + 2048), 3072, 1024);
    // per-token attention (one wave per token, 4 waves/block, no LDS/barrier)
    attn_mfma_kernel<<<4096, 256, 0, stream>>>(qkv, ao);
    // GEMM2: out = ao @ woutT^T (fp32 out), N=1024, grid 256, C stride 1024
    gemm_bt<0><<<256, 512, 0, stream>>>(ao, woutT, (void*)out, 1024, 1024);
}